// Round 13
// baseline (257.465 us; speedup 1.0000x reference)
//
#include <hip/hip_runtime.h>
#include <hip/hip_bf16.h>

#define B_ 4
#define T_ 256
#define S_ 256
#define D_ 512
#define TB 2   // t's per attention block

typedef __bf16 bf16x8 __attribute__((ext_vector_type(8)));
typedef float  floatx4 __attribute__((ext_vector_type(4)));

#define C2F 2.885390081777926f  // 2*log2(e)
#define NBLK 512u

static __device__ __forceinline__ unsigned short f2bf(float x) {
    __hip_bfloat16 h = __float2bfloat16(x);
    return *reinterpret_cast<unsigned short*>(&h);
}
static __device__ __forceinline__ float asf(unsigned int u) {
    float f; __builtin_memcpy(&f, &u, 4); return f;
}

struct MP {
    const float* output; const float* context; const int* mask;
    const float* Wq; const float* bq; const float* Wc; const float* v;
    const float* Wout; const float* bout;
    float* attn_out; float* out;
    float* wqs; float* OB;
    unsigned short* uhb; unsigned short* CWb;
    unsigned int* bar;
};

// ---------------------------------------------------------------------------
// ONE kernel, 512 blocks x 1024 threads. Exact-capacity co-residency:
// 1024 thr/block, 2 blocks/CU (launch_bounds(1024,8) caps VGPR<=64), 512
// block slots = 512 blocks -> every block is resident before any can pass
// the hand-rolled grid barrier (spin on device-scope atomic; counter zeroed
// by hipMemsetAsync before launch). No cooperative API (fails graph capture).
//
// Phase 1 (bid = z + 4*(nblk + 8*mblk)): four GEMMs, 64m x 64n x K=512 tile
// per block, fp32 inputs converted inline to bf16, LDS-staged in MFMA
// fragment order; 16 waves/tile, 1 MFMA + 2 ds_read_b128 per 32-k chunk:
//   z0: wqs = C2*(output@Wq + bq)            fp32
//   z1: uhb = bf16 C2*(context@Wc)           [b][d/8][s][8]
//   z2: OB  = output@Wout[512:] + bout       fp32
//   z3: CWb = bf16 context@Wout[:512]        natural [row][col]
//
// grid barrier (threadfence + device atomicAdd + acquire spin)
//
// Phase 2: score + masked softmax + out-projection (R11 attn, known-good
// 43.8 us) with explicit u4 double-buffer prefetch in the score loop.
// ---------------------------------------------------------------------------
__global__ __launch_bounds__(1024, 8) void mega(MP P)
{
    const int tid = threadIdx.x;
    const int bid = blockIdx.x;

    // phase-1 LDS
    __shared__ unsigned short Af[4 * 64 * 8];  // 4 KB, frag order
    __shared__ unsigned short Bf[4 * 64 * 8];  // 4 KB
    // phase-2 LDS
    __shared__ float  w_s[TB][D_];       // 4 KB
    __shared__ float  v_s[D_];           // 2 KB
    __shared__ float2 part[4][256];      // 8 KB
    __shared__ float2 wred[4];
    __shared__ float  a_s[TB][256];      // 2 KB
    __shared__ float  mixp[4][TB][D_];   // 16 KB

    // ======================= PHASE 1: four GEMMs =======================
    {
        const int z  = bid & 3;
        const int n0 = ((bid >> 2) & 7) * 64;
        const int m0 = (bid >> 5) * 64;

        const float* A; const float* W; const float* aux; int krow0, mode;
        if      (z == 0) { A = P.output;  W = P.Wq;   aux = P.bq;    krow0 = 0;   mode = 1; }
        else if (z == 1) { A = P.context; W = P.Wc;   aux = nullptr; krow0 = 0;   mode = 3; }
        else if (z == 2) { A = P.output;  W = P.Wout; aux = P.bout;  krow0 = 512; mode = 4; }
        else             { A = P.context; W = P.Wout; aux = nullptr; krow0 = 0;   mode = 5; }

        // staging: A chunk 64m x 32k, B chunk 32k x 64n; 2 elems/thread each
        const int am = tid >> 4;              // 0..63
        const int ak = (tid & 15) * 2;        // 0..30 even
        const int bn = tid & 63;
        const int bk = (tid >> 6) * 2;        // 0..30 even

        const float* Aptr = A + (size_t)(m0 + am) * 512 + ak;
        const float* Wptr = W + (size_t)(krow0 + bk) * 512 + n0 + bn;

        unsigned int* Awr = (unsigned int*)&Af[((am >> 4) * 64
                              + ((am & 15) | ((ak >> 3) << 4))) * 8 + (ak & 7)];
        unsigned int* Bwr = (unsigned int*)&Bf[((bn >> 4) * 64
                              + ((bn & 15) | ((bk >> 3) << 4))) * 8 + (bk & 7)];

        const int wave = tid >> 6, lane = tid & 63;
        const int l15 = lane & 15, quad = lane >> 4;
        const int mf = wave >> 2, nf = wave & 3;
        const unsigned short* Ard = &Af[(mf * 64 + lane) * 8];
        const unsigned short* Brd = &Bf[(nf * 64 + lane) * 8];

        floatx4 acc = (floatx4){0.f, 0.f, 0.f, 0.f};

        for (int chunk = 0; chunk < 16; ++chunk) {
            const int k0 = chunk * 32;
            float2 av = *(const float2*)(Aptr + k0);
            float  b0 = Wptr[(size_t)k0 * 512];
            float  b1 = Wptr[(size_t)k0 * 512 + 512];

            __syncthreads();   // prev chunk's frag reads done
            *Awr = (unsigned)f2bf(av.x) | ((unsigned)f2bf(av.y) << 16);
            *Bwr = (unsigned)f2bf(b0)   | ((unsigned)f2bf(b1)   << 16);
            __syncthreads();

            bf16x8 fa = *(const bf16x8*)Ard;
            bf16x8 fb = *(const bf16x8*)Brd;
            acc = __builtin_amdgcn_mfma_f32_16x16x32_bf16(fa, fb, acc, 0, 0, 0);
        }

        const int col = n0 + nf * 16 + l15;
        const int rbase = m0 + mf * 16 + quad * 4;
        if (mode == 3) {
            #pragma unroll
            for (int r = 0; r < 4; ++r) {
                int row = rbase + r, bb = row >> 8, ss = row & 255;
                P.uhb[((size_t)(bb * 64 + (col >> 3)) * 256 + ss) * 8 + (col & 7)]
                    = f2bf(C2F * acc[r]);
            }
        } else if (mode == 5) {
            #pragma unroll
            for (int r = 0; r < 4; ++r)
                P.CWb[(size_t)(rbase + r) * 512 + col] = f2bf(acc[r]);
        } else {
            float* Cf = (mode == 1) ? P.wqs : P.OB;
            float bv = aux ? aux[col] : 0.0f;
            #pragma unroll
            for (int r = 0; r < 4; ++r) {
                float val = acc[r] + bv;
                if (mode == 1) val *= C2F;
                Cf[(size_t)(rbase + r) * 512 + col] = val;
            }
        }
    }

    // =================== hand-rolled grid barrier =====================
    __syncthreads();                    // whole block's phase-1 stores issued
    if (tid == 0) {
        __threadfence();                // device-scope release of our writes
        atomicAdd(P.bar, 1u);           // device-scope by default
        while (__hip_atomic_load(P.bar, __ATOMIC_ACQUIRE,
                                 __HIP_MEMORY_SCOPE_AGENT) < NBLK) { }
    }
    __syncthreads();                    // rest of block waits on tid0

    // ======================= PHASE 2: attn ============================
    {
        const int bg  = bid;
        const int b   = bg / (T_ / TB);
        const int t0  = (bg % (T_ / TB)) * TB;
        const int s   = tid & 255;
        const int h   = tid >> 8;    // 0..3

        if (tid < 512) {
            w_s[0][tid] = P.wqs[(size_t)(b * T_ + t0 + 0) * D_ + tid];
            w_s[1][tid] = P.wqs[(size_t)(b * T_ + t0 + 1) * D_ + tid];
            v_s[tid]    = P.v[tid];
        }
        __syncthreads();

        float acc0 = 0.f, acc1 = 0.f;
        const int dd0 = h * 16;
        const uint4* u4 = (const uint4*)(P.uhb + ((size_t)(b * 64 + dd0) * 256 + s) * 8);

        uint4 uu = u4[0];                       // prefetch depth 1
        #pragma unroll 4
        for (int dd = 0; dd < 16; ++dd) {
            uint4 cur = uu;
            if (dd < 15) uu = u4[(size_t)(dd + 1) * 256];
            float uf[8];
            uf[0] = asf(cur.x << 16); uf[1] = asf(cur.x & 0xffff0000u);
            uf[2] = asf(cur.y << 16); uf[3] = asf(cur.y & 0xffff0000u);
            uf[4] = asf(cur.z << 16); uf[5] = asf(cur.z & 0xffff0000u);
            uf[6] = asf(cur.w << 16); uf[7] = asf(cur.w & 0xffff0000u);

            const int dbase = (dd0 + dd) * 8;
            #pragma unroll
            for (int j = 0; j < 8; ++j) {
                float vv = v_s[dbase + j];
                float x0 = w_s[0][dbase + j] + uf[j];
                float x1 = w_s[1][dbase + j] + uf[j];
                float r0 = __builtin_amdgcn_rcpf(__builtin_amdgcn_exp2f(x0) + 1.0f);
                float r1 = __builtin_amdgcn_rcpf(__builtin_amdgcn_exp2f(x1) + 1.0f);
                acc0 = fmaf(vv, r0, acc0);
                acc1 = fmaf(vv, r1, acc1);
            }
        }
        part[h][s] = make_float2(acc0, acc1);
        __syncthreads();

        float p0 = 0.f, p1 = 0.f;
        if (tid < 256) {
            float A0 = part[0][tid].x + part[1][tid].x + part[2][tid].x + part[3][tid].x;
            float A1 = part[0][tid].y + part[1][tid].y + part[2][tid].y + part[3][tid].y;
            float keep = 1.0f - (float)P.mask[b * S_ + tid];
            p0 = __builtin_amdgcn_exp2f(-C2F * A0) * keep;
            p1 = __builtin_amdgcn_exp2f(-C2F * A1) * keep;
            float s0 = p0, s1 = p1;
            #pragma unroll
            for (int off = 1; off < 64; off <<= 1) {
                s0 += __shfl_xor(s0, off);
                s1 += __shfl_xor(s1, off);
            }
            if ((tid & 63) == 0) wred[tid >> 6] = make_float2(s0, s1);
        }
        __syncthreads();

        if (tid < 256) {
            float den0 = wred[0].x + wred[1].x + wred[2].x + wred[3].x;
            float den1 = wred[0].y + wred[1].y + wred[2].y + wred[3].y;
            float a0 = p0 * __builtin_amdgcn_rcpf(den0);
            float a1 = p1 * __builtin_amdgcn_rcpf(den1);
            P.attn_out[(size_t)(b * T_ + t0 + 0) * S_ + tid] = a0;
            P.attn_out[(size_t)(b * T_ + t0 + 1) * S_ + tid] = a1;
            a_s[0][tid] = a0;
            a_s[1][tid] = a1;
        }
        __syncthreads();

        const int d2 = tid & 255;
        const int sh = h * 64;
        const unsigned short* cw = P.CWb + ((size_t)(b * S_) + sh) * D_ + 2 * d2;
        float m[TB][2] = {};
        #pragma unroll 8
        for (int s2 = 0; s2 < 64; ++s2) {
            unsigned int cc = *(const unsigned int*)(cw + (size_t)s2 * D_);
            float c0 = asf(cc << 16), c1 = asf(cc & 0xffff0000u);
            #pragma unroll
            for (int t = 0; t < TB; ++t) {
                float a = a_s[t][sh + s2];
                m[t][0] = fmaf(a, c0, m[t][0]);
                m[t][1] = fmaf(a, c1, m[t][1]);
            }
        }
        #pragma unroll
        for (int t = 0; t < TB; ++t) {
            mixp[h][t][2 * d2]     = m[t][0];
            mixp[h][t][2 * d2 + 1] = m[t][1];
        }
        __syncthreads();

        {
            const int t = tid >> 9, d = tid & 511;
            size_t idx = (size_t)(b * T_ + t0 + t) * D_ + d;
            P.out[idx] = mixp[0][t][d] + mixp[1][t][d] + mixp[2][t][d]
                       + mixp[3][t][d] + P.OB[idx];
        }
    }
}

extern "C" void kernel_launch(void* const* d_in, const int* in_sizes, int n_in,
                              void* d_out, int out_size, void* d_ws, size_t ws_size,
                              hipStream_t stream) {
    float* out  = (float*)d_out;                       // (B,T,D)
    float* attn = out + (size_t)B_ * T_ * D_;          // (B,T,S)

    char* ws = (char*)d_ws;
    MP P;
    P.output  = (const float*)d_in[0];
    P.context = (const float*)d_in[1];
    P.mask    = (const int*)d_in[2];
    P.Wq      = (const float*)d_in[3];
    P.bq      = (const float*)d_in[4];
    P.Wc      = (const float*)d_in[5];
    P.v       = (const float*)d_in[6];
    P.Wout    = (const float*)d_in[7];
    P.bout    = (const float*)d_in[8];
    P.attn_out = attn;
    P.out      = out;
    P.wqs = (float*)ws;                                   // 2 MB
    P.OB  = (float*)(ws + (2u << 20));                    // 2 MB
    P.uhb = (unsigned short*)(ws + (4u << 20));           // 1 MB
    P.CWb = (unsigned short*)(ws + (5u << 20));           // 1 MB
    P.bar = (unsigned int*)(ws + (10u << 20));            // 4 B barrier counter

    // zero the barrier counter (graph-legal async memset; d_ws is poisoned
    // 0xAA before every timed launch, so this must run every call)
    hipMemsetAsync(P.bar, 0, sizeof(unsigned int), stream);

    mega<<<dim3(NBLK), dim3(1024), 0, stream>>>(P);
}